// Round 3
// baseline (10.631 us; speedup 1.0000x reference)
//
#include <hip/hip_runtime.h>
#include <math.h>

#define IMG_SIZE 512
#define THRESH 160.0f
#define CHUNK 8

// One thread per sample. Step r=0 is degenerate: x=y=256 exactly for every
// sample (r multiplies the trig terms away), so its pixel test is a single
// wave-uniform scalar load and its distance is the constant sqrt(144^2+44^2)
// = sqrt(22672) (exact integers in f32 -> identical constant to numpy).
// Remaining steps r=1..511 are evaluated speculatively in chunks of 8 so the
// 8 scattered image-load latencies overlap; first-hit scan afterwards.
// All arithmetic is faithful-f32 (no FMA contraction, ocml sincos, trunc
// casts) and bit-identical to the numpy reference. sincosf shares the ocml
// range reduction used by sinf/cosf, producing bit-identical sin/cos.
__global__ __launch_bounds__(64) void euclid_loss_kernel(
    const float* __restrict__ coef,   // [B, 4]
    const float* __restrict__ image,  // [512, 512] row-major
    float* __restrict__ out,          // [B]
    int B)
{
    int b = blockIdx.x * blockDim.x + threadIdx.x;
    if (b >= B) return;

    const float4 c = reinterpret_cast<const float4*>(coef)[b];

    // --- step 0 (constant for all samples) ---
    float runmin = sqrtf(22672.0f);                // dist at (256,256), exact
    if (image[256 * IMG_SIZE + 256] < THRESH) {    // wave-uniform scalar load
        out[b] = runmin;
        return;
    }

    bool done = false;

    // --- full chunks: r = 1..504 (63 chunks of 8, no bounds guards) ---
    for (int base = 1; base + CHUNK <= IMG_SIZE && !done; base += CHUNK) {
        float dist[CHUNK];
        float px[CHUNK];

        #pragma unroll
        for (int k = 0; k < CHUNK; ++k) {
            const float r  = (float)(base + k);
            const float r2 = __fmul_rn(r, r);      // exact below 2^24
            const float r3 = __fmul_rn(r2, r);     // single rounding == powf

            float theta = c.x;
            theta = __fadd_rn(theta, __fmul_rn(c.y, r));
            theta = __fadd_rn(theta, __fmul_rn(c.z, r2));
            theta = __fadd_rn(theta, __fmul_rn(c.w, r3));

            float st, ct;
            sincosf(theta, &st, &ct);              // shared ocml reduction

            const float x = __fadd_rn(256.0f, __fmul_rn(r, ct));
            const float y = __fadd_rn(256.0f, __fmul_rn(r, st));

            const float dx = __fsub_rn(x, 400.0f);
            const float dy = __fsub_rn(y, 300.0f);
            dist[k] = sqrtf(__fadd_rn(__fmul_rn(dx, dx), __fmul_rn(dy, dy)));

            int xi = (int)x;                       // trunc toward zero
            int yi = (int)y;
            xi = max(0, min(IMG_SIZE - 1, xi));
            yi = max(0, min(IMG_SIZE - 1, yi));
            px[k] = image[xi * IMG_SIZE + yi];     // loads overlap in flight
        }

        #pragma unroll
        for (int k = 0; k < CHUNK; ++k) {
            if (!done) {
                runmin = fminf(runmin, dist[k]);   // min BEFORE exit test
                if (px[k] < THRESH) done = true;
            }
        }
    }

    // --- tail: r = 505..511 (reached with prob ~1e-13 per lane) ---
    if (!done) {
        for (int ri = ((IMG_SIZE - 1 - 1) / CHUNK) * CHUNK + 1; ri < IMG_SIZE; ++ri) {
            const float r  = (float)ri;
            const float r2 = __fmul_rn(r, r);
            const float r3 = __fmul_rn(r2, r);

            float theta = c.x;
            theta = __fadd_rn(theta, __fmul_rn(c.y, r));
            theta = __fadd_rn(theta, __fmul_rn(c.z, r2));
            theta = __fadd_rn(theta, __fmul_rn(c.w, r3));

            float st, ct;
            sincosf(theta, &st, &ct);

            const float x = __fadd_rn(256.0f, __fmul_rn(r, ct));
            const float y = __fadd_rn(256.0f, __fmul_rn(r, st));

            const float dx = __fsub_rn(x, 400.0f);
            const float dy = __fsub_rn(y, 300.0f);
            const float dist =
                sqrtf(__fadd_rn(__fmul_rn(dx, dx), __fmul_rn(dy, dy)));

            runmin = fminf(runmin, dist);

            int xi = (int)x;
            int yi = (int)y;
            xi = max(0, min(IMG_SIZE - 1, xi));
            yi = max(0, min(IMG_SIZE - 1, yi));
            if (image[xi * IMG_SIZE + yi] < THRESH) break;
        }
    }

    out[b] = runmin;
}

extern "C" void kernel_launch(void* const* d_in, const int* in_sizes, int n_in,
                              void* d_out, int out_size, void* d_ws, size_t ws_size,
                              hipStream_t stream) {
    const float* coef  = (const float*)d_in[0];   // [B,4] float32
    const float* image = (const float*)d_in[1];   // [512,512] float32
    float* out = (float*)d_out;                   // [B] float32

    const int B = in_sizes[0] / 4;
    const int block = 64;
    const int grid  = (B + block - 1) / block;
    euclid_loss_kernel<<<grid, block, 0, stream>>>(coef, image, out, B);
}

// Round 4
// 9.355 us; speedup vs baseline: 1.1363x; 1.1363x over previous
//
#include <hip/hip_runtime.h>
#include <math.h>

#define IMG_SIZE 512
#define THRESH 160.0f
#define CHUNK 8

// One thread per sample. Steps are independent except for the first-hit scan,
// so evaluate CHUNK steps speculatively: compute 8 thetas/sincos, issue all 8
// image loads (latencies overlap), then scan in order for the exit. Arithmetic
// per step is bit-identical to the serial version (no FMA, ocml sin/cos,
// trunc casts) so outputs remain exact vs the numpy reference.
// NOTE: separate sinf/cosf on the same theta share their range reduction via
// inlining+CSE; sincosf's pointer outputs measured SLOWER (R3: 10.63 vs 9.35).
__global__ __launch_bounds__(64) void euclid_loss_kernel(
    const float* __restrict__ coef,   // [B, 4]
    const float* __restrict__ image,  // [512, 512] row-major
    float* __restrict__ out,          // [B]
    int B)
{
    int b = blockIdx.x * blockDim.x + threadIdx.x;
    if (b >= B) return;

    const float4 c = reinterpret_cast<const float4*>(coef)[b];

    float runmin = INFINITY;
    bool done = false;

    for (int base = 0; base < IMG_SIZE && !done; base += CHUNK) {
        float dist[CHUNK];
        float px[CHUNK];

        #pragma unroll
        for (int k = 0; k < CHUNK; ++k) {
            const float r  = (float)(base + k);
            const float r2 = __fmul_rn(r, r);          // exact below 2^24
            const float r3 = __fmul_rn(r2, r);         // single rounding == powf

            float theta = c.x;
            theta = __fadd_rn(theta, __fmul_rn(c.y, r));
            theta = __fadd_rn(theta, __fmul_rn(c.z, r2));
            theta = __fadd_rn(theta, __fmul_rn(c.w, r3));

            const float ct = cosf(theta);              // accurate ocml
            const float st = sinf(theta);

            const float x = __fadd_rn(256.0f, __fmul_rn(r, ct));
            const float y = __fadd_rn(256.0f, __fmul_rn(r, st));

            const float dx = __fsub_rn(x, 400.0f);
            const float dy = __fsub_rn(y, 300.0f);
            dist[k] = sqrtf(__fadd_rn(__fmul_rn(dx, dx), __fmul_rn(dy, dy)));

            int xi = (int)x;                           // trunc toward zero
            int yi = (int)y;
            xi = max(0, min(IMG_SIZE - 1, xi));
            yi = max(0, min(IMG_SIZE - 1, yi));
            px[k] = image[xi * IMG_SIZE + yi];         // issued per k; waits
        }                                              // coalesce before use

        #pragma unroll
        for (int k = 0; k < CHUNK; ++k) {
            if (!done) {
                runmin = fminf(runmin, dist[k]);       // min BEFORE exit test
                if (px[k] < THRESH) done = true;
            }
        }
    }

    out[b] = runmin;
}

extern "C" void kernel_launch(void* const* d_in, const int* in_sizes, int n_in,
                              void* d_out, int out_size, void* d_ws, size_t ws_size,
                              hipStream_t stream) {
    const float* coef  = (const float*)d_in[0];   // [B,4] float32
    const float* image = (const float*)d_in[1];   // [512,512] float32
    float* out = (float*)d_out;                   // [B] float32

    const int B = in_sizes[0] / 4;
    const int block = 64;
    const int grid  = (B + block - 1) / block;
    euclid_loss_kernel<<<grid, block, 0, stream>>>(coef, image, out, B);
}